// Round 20
// baseline (1646.262 us; speedup 1.0000x reference)
//
#include <hip/hip_runtime.h>
#include <hip/hip_bf16.h>

// ---------------------------------------------------------------------------
// MatchingNetwork forward. Conv trunk fully f16-MFMA (f32 accumulate).
// R20: conv64m rewritten (old version had a coverage bug: 4-row tiles on an
// 8-row grid stride; rows 4-7 mod 8 were zeros from OOB-LDS garbage). New:
// halo-tile (10x18x64 f16) staged once, B-fragments register-resident per
// wave (1 co-tile/wave), 144 MFMA with ONE barrier, in-register stats+pool.
// L2/L3 pooled pre-BN stored f16 (R19-proven safe), in-place BN.
// Activations: [g*32+i][h][w][c], c=64 contiguous.
// ---------------------------------------------------------------------------

#define NG 25
#define NI 32

typedef _Float16 half8v __attribute__((ext_vector_type(8)));
typedef __attribute__((ext_vector_type(4))) float float4v;

__device__ __forceinline__ unsigned short f2h(float f) {
    _Float16 h = (_Float16)f;   // RNE
    union { _Float16 h; unsigned short u; } cv; cv.h = h;
    return cv.u;
}
__device__ __forceinline__ float h2f(unsigned short u) {
    union { unsigned short u; _Float16 h; } cv; cv.u = u;
    return (float)cv.h;
}

__device__ __forceinline__ float fsigm(float x) {
    return __builtin_amdgcn_rcpf(1.f + exp2f(-1.44269504f * x));
}
__device__ __forceinline__ float ftanh(float x) {
    return 1.f - 2.f * __builtin_amdgcn_rcpf(1.f + exp2f(2.88539008f * x));
}

__device__ __forceinline__ void pstore(float* p, size_t off, float v) { p[off] = v; }
__device__ __forceinline__ void pstore(unsigned short* p, size_t off, float v) { p[off] = f2h(v); }

// ---------------- weights f32 [tap][ci][co] -> f16 transposed [tap][co][ci] -
__global__ __launch_bounds__(256)
void wcvt_kernel(const float* __restrict__ wk, unsigned short* __restrict__ w16t) {
    int tap = blockIdx.x;
    for (int e = threadIdx.x; e < 4096; e += 256) {
        int co = e >> 6, ci = e & 63;
        w16t[(size_t)tap * 4096 + e] = f2h(wk[(size_t)tap * 4096 + ci * 64 + co]);
    }
}

// ---------------- Layer 1: f16 MFMA conv(CIN=3) + stats + in-reg pool -------
__global__ __launch_bounds__(256)
void conv3m_kernel(const float* __restrict__ xs, const float* __restrict__ xq,
                   const float* __restrict__ wk, unsigned short* __restrict__ pool1h,
                   float* __restrict__ part, int g0) {
    __shared__ _Float16 sIn[10][304];   // [.][294..303] guaranteed zeros
    __shared__ float sred[4][2][64];
    int gi = blockIdx.x;
    int gl = gi >> 5, i = gi & 31;
    int g = g0 + gl;
    int band = blockIdx.y;
    const float* base = (g < 20) ? xs + (size_t)(i * 20 + g) * (84 * 84 * 3)
                                 : xq + (size_t)(i * 5 + (g - 20)) * (84 * 84 * 3);
    int r0 = band * 8;
    for (int p = threadIdx.x; p < 10 * 152; p += 256) {
        int rr = p / 152, ep = (p - rr * 152) * 2;
        int r = r0 - 1 + rr;
        float v0 = 0.f, v1 = 0.f;
        if (ep < 294 && (unsigned)r < 84u) {
            int col0 = ep / 3 - 1, ci0 = ep - (ep / 3) * 3;
            if ((unsigned)col0 < 84u) v0 = base[((size_t)r * 84 + col0) * 3 + ci0];
            int e1 = ep + 1;
            if (e1 < 294) {
                int col1 = e1 / 3 - 1, ci1 = e1 - (e1 / 3) * 3;
                if ((unsigned)col1 < 84u) v1 = base[((size_t)r * 84 + col1) * 3 + ci1];
            }
        }
        unsigned int pk = (unsigned int)f2h(v0) | ((unsigned int)f2h(v1) << 16);
        ((unsigned int*)&sIn[rr][0])[p - rr * 152] = pk;
    }
    int lane = threadIdx.x & 63;
    int wv = threadIdx.x >> 6;
    int gq = lane >> 4;
    int l16 = lane & 15;
    int rowo[8], eo[8]; bool kv[8];
    #pragma unroll
    for (int j = 0; j < 8; ++j) {
        int k = 8 * gq + j;
        kv[j] = (k < 27);
        int kk = kv[j] ? k : 0;
        int kh = kk / 9; int rem = kk - kh * 9; int kw = rem / 3; int ci = rem - kw * 3;
        rowo[j] = kv[j] ? kh : 0;
        eo[j] = kw * 3 + ci;
    }
    half8v bfr[4];
    #pragma unroll
    for (int ct = 0; ct < 4; ++ct)
        #pragma unroll
        for (int j = 0; j < 8; ++j) {
            int k = 8 * gq + j;
            float w = (k < 27) ? wk[(size_t)k * 64 + ct * 16 + l16] : 0.f;
            bfr[ct][j] = (_Float16)w;
        }
    __syncthreads();

    bool rowv = (r0 + 2 * wv) < 84;
    int prow = band * 4 + wv;
    int sr = 2 * wv;
    float sA[4] = {0.f, 0.f, 0.f, 0.f}, sB[4] = {0.f, 0.f, 0.f, 0.f};

    #pragma unroll 1
    for (int tile = 0; tile < 6; ++tile) {
        int c0 = tile * 16;
        int w = c0 + l16;
        int eoff[8];
        #pragma unroll
        for (int j = 0; j < 8; ++j) eoff[j] = kv[j] ? (w * 3 + eo[j]) : 294;
        float4v acc0[4], acc1[4];
        #pragma unroll
        for (int ct = 0; ct < 4; ++ct) {
            acc0[ct] = (float4v){0.f, 0.f, 0.f, 0.f};
            acc1[ct] = (float4v){0.f, 0.f, 0.f, 0.f};
        }
        #pragma unroll
        for (int rs = 0; rs < 2; ++rs) {
            half8v af;
            #pragma unroll
            for (int j = 0; j < 8; ++j)
                af[j] = sIn[sr + rs + rowo[j]][eoff[j]];
            if (rs == 0) {
                #pragma unroll
                for (int ct = 0; ct < 4; ++ct)
                    acc0[ct] = __builtin_amdgcn_mfma_f32_16x16x32_f16(af, bfr[ct], acc0[ct], 0, 0, 0);
            } else {
                #pragma unroll
                for (int ct = 0; ct < 4; ++ct)
                    acc1[ct] = __builtin_amdgcn_mfma_f32_16x16x32_f16(af, bfr[ct], acc1[ct], 0, 0, 0);
            }
        }
        #pragma unroll
        for (int ct = 0; ct < 4; ++ct) {
            #pragma unroll
            for (int r = 0; r < 4; ++r) {
                float a0 = acc0[ct][r], a1 = acc1[ct][r];
                sA[ct] += a0 + a1;
                sB[ct] = fmaf(a0, a0, fmaf(a1, a1, sB[ct]));
            }
            if (rowv) {
                float m01 = fmaxf(fmaxf(acc0[ct][0], acc0[ct][1]),
                                  fmaxf(acc1[ct][0], acc1[ct][1]));
                float m23 = fmaxf(fmaxf(acc0[ct][2], acc0[ct][3]),
                                  fmaxf(acc1[ct][2], acc1[ct][3]));
                int pc0 = (c0 + gq * 4) >> 1;
                size_t rowbase = (((size_t)gi * 42 + prow) * 42) * 64 + ct * 16 + l16;
                if (pc0 < 42)     pool1h[rowbase + (size_t)pc0 * 64] = f2h(m01);
                if (pc0 + 1 < 42) pool1h[rowbase + (size_t)(pc0 + 1) * 64] = f2h(m23);
            }
        }
    }
    #pragma unroll
    for (int ct = 0; ct < 4; ++ct) {
        float s = sA[ct], q = sB[ct];
        s += __shfl_xor(s, 16); s += __shfl_xor(s, 32);
        q += __shfl_xor(q, 16); q += __shfl_xor(q, 32);
        if (gq == 0) { sred[wv][0][ct * 16 + l16] = s; sred[wv][1][ct * 16 + l16] = q; }
    }
    __syncthreads();
    if (threadIdx.x < 64) {
        int co = threadIdx.x;
        float s = sred[0][0][co] + sred[1][0][co] + sred[2][0][co] + sred[3][0][co];
        float q = sred[0][1][co] + sred[1][1][co] + sred[2][1][co] + sred[3][1][co];
        size_t pr = (size_t)blockIdx.y * gridDim.x + blockIdx.x;
        part[pr * 128 + co] = s;
        part[pr * 128 + 64 + co] = q;
    }
}

// ---------------- Layers 2-4: halo-tile f16 MFMA conv + stats + pool --------
// Block = 4 waves; tile 8 rows x 16 cols = 128 positions x 64 co. Wave wv
// owns co-tile wv (B fragments in registers). Halo [10][18][64] f16 staged
// once (col stride 72 for banking/alignment). ONE barrier total.
template<int D, typename OutT>
__global__ __launch_bounds__(256, 3)
void conv64m_kernel(const unsigned short* __restrict__ act16,
                    const unsigned short* __restrict__ w16t,
                    OutT* __restrict__ poolout, float* __restrict__ part) {
    constexpr int nCT = (D + 15) / 16;
    constexpr int PD = D / 2;
    __shared__ __align__(16) unsigned short sH[10 * 18 * 72];  // 25,920 B
    int gi = blockIdx.x;
    int rt = blockIdx.y / nCT, ctile = blockIdx.y % nCT;
    int r0 = rt * 8, c0 = ctile * 16;
    const unsigned short* in = act16 + (size_t)gi * D * D * 64;

    int lane = threadIdx.x & 63;
    int wv = threadIdx.x >> 6;
    int gq = lane >> 4;
    int l16 = lane & 15;

    // B fragments (9 taps x 2 k-steps) for this wave's co-tile, in registers
    half8v bfr[9][2];
    #pragma unroll
    for (int tap = 0; tap < 9; ++tap)
        #pragma unroll
        for (int ks = 0; ks < 2; ++ks)
            bfr[tap][ks] = *(const half8v*)&w16t[((size_t)tap * 64 + wv * 16 + l16) * 64 + ks * 32 + gq * 8];

    // stage halo tile: rows r0-1..r0+8, cols c0-1..c0+16, 64 ci (zeros OOB)
    for (int s = threadIdx.x; s < 10 * 18 * 8; s += 256) {
        int row = s / 144, rem = s - row * 144;
        int col = rem >> 3, q = rem & 7;
        int h = r0 + row - 1, w = c0 + col - 1;
        uint4 v = {0, 0, 0, 0};
        if ((unsigned)h < (unsigned)D && (unsigned)w < (unsigned)D)
            v = *(const uint4*)&in[((size_t)h * D + w) * 64 + q * 8];
        *(uint4*)&sH[row * 1296 + col * 72 + q * 8] = v;
    }
    __syncthreads();

    float4v acc[8];
    #pragma unroll
    for (int m = 0; m < 8; ++m) acc[m] = (float4v){0.f, 0.f, 0.f, 0.f};

    int abase = (l16) * 72 + gq * 8;   // col base for this lane (l16+kw handled by imm)
    #pragma unroll
    for (int tap = 0; tap < 9; ++tap) {
        constexpr int dummy = 0; (void)dummy;
        const int kh = tap / 3, kw = tap - (tap / 3) * 3;
        #pragma unroll
        for (int ks = 0; ks < 2; ++ks) {
            #pragma unroll
            for (int m = 0; m < 8; ++m) {
                half8v af = *(const half8v*)&sH[(m + kh) * 1296 + kw * 72 + ks * 32 + abase];
                acc[m] = __builtin_amdgcn_mfma_f32_16x16x32_f16(af, bfr[tap][ks], acc[m], 0, 0, 0);
            }
        }
    }

    // stats: lane's co = wv*16+l16; sum over 8 m x 4 r; reduce over gq groups
    {
        float s = 0.f, s2 = 0.f;
        #pragma unroll
        for (int m = 0; m < 8; ++m)
            #pragma unroll
            for (int r = 0; r < 4; ++r) {
                float a = acc[m][r];
                s += a; s2 = fmaf(a, a, s2);
            }
        s += __shfl_xor(s, 16); s += __shfl_xor(s, 32);
        s2 += __shfl_xor(s2, 16); s2 += __shfl_xor(s2, 32);
        if (gq == 0) {
            size_t prow = (size_t)blockIdx.y * gridDim.x + blockIdx.x;
            part[prow * 128 + wv * 16 + l16] = s;
            part[prow * 128 + 64 + wv * 16 + l16] = s2;
        }
    }
    // in-register 2x2 pool. D-layout: acc[m][r] = conv(row r0+m, col c0+gq*4+r),
    // co = wv*16+l16. Row pairs (2p,2p+1); col pairs (gq*4+0,1) and (gq*4+2,3).
    int ch = wv * 16 + l16;
    #pragma unroll
    for (int p = 0; p < 4; ++p) {
        float m01 = fmaxf(fmaxf(acc[2 * p][0], acc[2 * p][1]),
                          fmaxf(acc[2 * p + 1][0], acc[2 * p + 1][1]));
        float m23 = fmaxf(fmaxf(acc[2 * p][2], acc[2 * p][3]),
                          fmaxf(acc[2 * p + 1][2], acc[2 * p + 1][3]));
        int gpr = rt * 4 + p;
        int gpc0 = ctile * 8 + gq * 2;
        if (gpr < PD) {
            size_t rb = (((size_t)gi * PD + gpr) * PD) * 64 + ch;
            if (gpc0 < PD)     pstore(poolout, rb + (size_t)gpc0 * 64, m01);
            if (gpc0 + 1 < PD) pstore(poolout, rb + (size_t)(gpc0 + 1) * 64, m23);
        }
    }
}

// bn_finalize: one (group, channel) per block. grid (ngc, 64).
__global__ __launch_bounds__(256)
void bn_finalize_kernel(const float* __restrict__ part,
                        const float* __restrict__ gamma,
                        const float* __restrict__ beta,
                        float* __restrict__ bnp, float invN, int nby, int gridx) {
    int g = blockIdx.x;
    int c = blockIdx.y;
    int nrows = nby * 32;
    float s = 0.f, s2 = 0.f;
    for (int rr = threadIdx.x; rr < nrows; rr += 256) {
        int by = rr >> 5, i = rr & 31;
        size_t row = (size_t)by * gridx + g * 32 + i;
        s  += part[row * 128 + c];
        s2 += part[row * 128 + 64 + c];
    }
    __shared__ float red[2][256];
    red[0][threadIdx.x] = s; red[1][threadIdx.x] = s2;
    __syncthreads();
    #pragma unroll
    for (int o = 128; o > 0; o >>= 1) {
        if (threadIdx.x < o) {
            red[0][threadIdx.x] += red[0][threadIdx.x + o];
            red[1][threadIdx.x] += red[1][threadIdx.x + o];
        }
        __syncthreads();
    }
    if (threadIdx.x == 0) {
        s = red[0][0]; s2 = red[1][0];
        float mean = s * invN;
        float var  = s2 * invN - mean * mean;
        float sc = gamma[c] * rsqrtf(var + 1e-3f);
        bnp[g * 128 + c] = sc;
        bnp[g * 128 + 64 + c] = beta[c] - sc * mean;
    }
}

// BN+ReLU in place on f16 buffer (L1/L2/L3 paths).
__global__ __launch_bounds__(256)
void bnapplyh_ip_kernel(unsigned short* __restrict__ buf, const float* __restrict__ bnp,
                        int PP, int total) {
    int v = blockIdx.x * 256 + threadIdx.x;
    if (v >= total) return;
    int c4 = (v & 15) * 4;
    int pos = v >> 4;
    int gi = pos / PP;
    int gl = gi >> 5;
    float4 sc = *(const float4*)&bnp[gl * 128 + c4];
    float4 sh = *(const float4*)&bnp[gl * 128 + 64 + c4];
    ushort4 x = *(const ushort4*)&buf[(size_t)pos * 64 + c4];
    ushort4 o;
    o.x = f2h(fmaxf(0.f, fmaf(sc.x, h2f(x.x), sh.x)));
    o.y = f2h(fmaxf(0.f, fmaf(sc.y, h2f(x.y), sh.y)));
    o.z = f2h(fmaxf(0.f, fmaf(sc.z, h2f(x.z), sh.z)));
    o.w = f2h(fmaxf(0.f, fmaf(sc.w, h2f(x.w), sh.w)));
    *(ushort4*)&buf[(size_t)pos * 64 + c4] = o;
}

// In-place f32 BN+ReLU (L4 emb path only).
__global__ __launch_bounds__(256)
void bnapply_kernel(float* __restrict__ buf, const float* __restrict__ bnp,
                    int PP, int total) {
    int v = blockIdx.x * 256 + threadIdx.x;
    if (v >= total) return;
    int c4 = (v & 15) * 4;
    int pos = v >> 4;
    int gi = pos / PP;
    int gl = gi >> 5;
    float4 sc = *(const float4*)&bnp[gl * 128 + c4];
    float4 sh = *(const float4*)&bnp[gl * 128 + 64 + c4];
    float4 x = *(const float4*)&buf[(size_t)pos * 64 + c4];
    float4 o;
    o.x = fmaxf(0.f, fmaf(sc.x, x.x, sh.x));
    o.y = fmaxf(0.f, fmaf(sc.y, x.y, sh.y));
    o.z = fmaxf(0.f, fmaf(sc.z, x.z, sh.z));
    o.w = fmaxf(0.f, fmaf(sc.w, x.w, sh.w));
    *(float4*)&buf[(size_t)pos * 64 + c4] = o;
}

// ---------------- xw projection: tiled split-K f32 GEMM ---------------------
__global__ __launch_bounds__(256)
void xw2_kernel(const float* __restrict__ emb, const float* __restrict__ fk,
                const float* __restrict__ bk, float* __restrict__ xwpart) {
    __shared__ float se[16][200];
    int rt = blockIdx.x;
    int kb = blockIdx.y;
    for (int idx = threadIdx.x; idx < 16 * 200; idx += 256) {
        int r = idx / 200, kk = idx - (idx / 200) * 200;
        se[r][kk] = emb[(size_t)(rt * 16 + r) * 1600 + kb * 200 + kk];
    }
    __syncthreads();
    int j = threadIdx.x & 127;
    int half = threadIdx.x >> 7;
    const float* Wm = half ? bk : fk;
    float acc[16];
    #pragma unroll
    for (int r = 0; r < 16; ++r) acc[r] = 0.f;
    for (int kk = 0; kk < 200; ++kk) {
        float w = Wm[(size_t)(kb * 200 + kk) * 128 + j];
        #pragma unroll
        for (int r = 0; r < 16; ++r) acc[r] = fmaf(se[r][kk], w, acc[r]);
    }
    #pragma unroll
    for (int r = 0; r < 16; ++r)
        xwpart[((size_t)kb * 800 + rt * 16 + r) * 256 + half * 128 + j] = acc[r];
}

__global__ __launch_bounds__(256)
void xwred_kernel(const float* __restrict__ xwpart, float* __restrict__ xwf,
                  float* __restrict__ xwb) {
    int gi = blockIdx.x;
    int c = threadIdx.x;
    float s = 0.f;
    #pragma unroll
    for (int kb = 0; kb < 8; ++kb)
        s += xwpart[((size_t)kb * 800 + gi) * 256 + c];
    if (c < 128) xwf[(size_t)gi * 128 + c] = s;
    else         xwb[(size_t)gi * 128 + (c - 128)] = s;
}

// ---------------- LSTM: latency-optimized, all state in registers -----------
__global__ __launch_bounds__(64, 1)
void lstm_kernel(const float* __restrict__ xwf, const float* __restrict__ xwb,
                 const float* __restrict__ fr, const float* __restrict__ fb,
                 const float* __restrict__ br, const float* __restrict__ bb,
                 float* __restrict__ Hs) {
    int g = blockIdx.x;
    int dir = blockIdx.y;
    int j = threadIdx.x;
    const float* xw = dir ? xwb : xwf;
    const float* Wr = dir ? br : fr;
    const float* bv = dir ? bb : fb;
    float frA[32], frB[32];
    #pragma unroll
    for (int k = 0; k < 32; ++k) {
        frA[k] = Wr[k * 128 + j];
        frB[k] = Wr[k * 128 + 64 + j];
    }
    float bA = bv[j], bB = bv[64 + j];
    float xA[32], xB[32];
    #pragma unroll
    for (int st = 0; st < 32; ++st) {
        int t = dir ? (31 - st) : st;
        xA[st] = xw[((size_t)g * NI + t) * 128 + j];
        xB[st] = xw[((size_t)g * NI + t) * 128 + 64 + j];
    }
    float h = 0.f, c = 0.f;
    #pragma unroll
    for (int st = 0; st < 32; ++st) {
        int t = dir ? (31 - st) : st;
        float a0 = xA[st] + bA, a1 = 0.f, a2 = 0.f, a3 = 0.f;
        float b0 = xB[st] + bB, b1 = 0.f, b2 = 0.f, b3 = 0.f;
        #pragma unroll
        for (int kk = 0; kk < 8; ++kk) {
            float h0 = __shfl(h, kk);
            float h1 = __shfl(h, kk + 8);
            float h2 = __shfl(h, kk + 16);
            float h3 = __shfl(h, kk + 24);
            a0 = fmaf(h0, frA[kk], a0);      b0 = fmaf(h0, frB[kk], b0);
            a1 = fmaf(h1, frA[kk + 8], a1);  b1 = fmaf(h1, frB[kk + 8], b1);
            a2 = fmaf(h2, frA[kk + 16], a2); b2 = fmaf(h2, frB[kk + 16], b2);
            a3 = fmaf(h3, frA[kk + 24], a3); b3 = fmaf(h3, frB[kk + 24], b3);
        }
        float accA = (a0 + a1) + (a2 + a3);
        float accB = (b0 + b1) + (b2 + b3);
        float ig = accA;
        float gg = accB;
        float fg = __shfl(accA, (j & 31) + 32);
        float og = __shfl(accB, (j & 31) + 32);
        float cn = fsigm(fg) * c + fsigm(ig) * ftanh(gg);
        float hn = fsigm(og) * ftanh(cn);
        if (j < 32) {
            c = cn; h = hn;
            Hs[((size_t)g * NI + t) * 64 + dir * 32 + j] = hn;
        }
    }
}

__global__ __launch_bounds__(64, 1)
void sim_kernel(const float* __restrict__ Hs, const int* __restrict__ ysup,
                const int* __restrict__ yq, float* __restrict__ ceb,
                float* __restrict__ eqb) {
    int q = blockIdx.x;
    int i = blockIdx.y;
    int lane = threadIdx.x;
    float qv = Hs[((size_t)(20 + q) * NI + i) * 64 + lane];
    float ls[20];
    for (int s = 0; s < 20; ++s) {
        float sv = Hs[((size_t)s * NI + i) * 64 + lane];
        float d = qv * sv;
        float m = sv * sv;
        #pragma unroll
        for (int o = 32; o > 0; o >>= 1) {
            d += __shfl_xor(d, o);
            m += __shfl_xor(m, o);
        }
        ls[s] = d * rsqrtf(fmaxf(m, 1e-10f));
    }
    if (lane == 0) {
        float mx = -1e30f;
        for (int s = 0; s < 20; ++s) mx = fmaxf(mx, ls[s]);
        float sum = 0.f, sim[20];
        for (int s = 0; s < 20; ++s) { sim[s] = expf(ls[s] - mx); sum += sim[s]; }
        float inv = 1.f / sum;
        float preds[20];
        for (int w = 0; w < 20; ++w) preds[w] = 0.f;
        for (int s = 0; s < 20; ++s) preds[ysup[i * 20 + s]] += sim[s] * inv;
        int y = yq[i * 5 + q];
        float pv = fminf(fmaxf(preds[y], 1e-7f), 1.f - 1e-7f);
        ceb[q * NI + i] = -logf(pv);
        int am = 0; float bm = preds[0];
        for (int w = 1; w < 20; ++w) if (preds[w] > bm) { bm = preds[w]; am = w; }
        eqb[q * NI + i] = (am == y) ? 1.f : 0.f;
    }
}

__global__ __launch_bounds__(64, 1)
void final_kernel(const float* __restrict__ ceb, const float* __restrict__ eqb,
                  float* __restrict__ out) {
    int lane = threadIdx.x;
    float e = 0.f;
    if (lane < 32) {
        float ce = 0.f;
        for (int q = 0; q < 5; ++q) { ce += ceb[q * NI + lane]; e += eqb[q * NI + lane]; }
        out[lane] = ce * 0.2f;
    }
    #pragma unroll
    for (int o = 32; o > 0; o >>= 1) e += __shfl_xor(e, o);
    if (lane == 0) out[32] = e / 160.f;
}

__global__ void sentinel_kernel(float* out) {
    if (threadIdx.x < 33) out[threadIdx.x] = -777.25f;
}

extern "C" void kernel_launch(void* const* d_in, const int* in_sizes, int n_in,
                              void* d_out, int out_size, void* d_ws, size_t ws_size,
                              hipStream_t stream) {
    const float* xs   = (const float*)d_in[0];
    const int*   ysup = (const int*)  d_in[1];
    const float* xq   = (const float*)d_in[2];
    const int*   yq   = (const int*)  d_in[3];
    const float* k[4]  = { (const float*)d_in[4],  (const float*)d_in[8],
                           (const float*)d_in[12], (const float*)d_in[16] };
    const float* ga[4] = { (const float*)d_in[6],  (const float*)d_in[10],
                           (const float*)d_in[14], (const float*)d_in[18] };
    const float* be[4] = { (const float*)d_in[7],  (const float*)d_in[11],
                           (const float*)d_in[15], (const float*)d_in[19] };
    const float* fk = (const float*)d_in[20];
    const float* fr = (const float*)d_in[21];
    const float* fb = (const float*)d_in[22];
    const float* bk = (const float*)d_in[23];
    const float* br = (const float*)d_in[24];
    const float* bb = (const float*)d_in[25];
    float* out = (float*)d_out;

    // per-group float-slot counts (all pools are f16 now)
    const size_t P1   = (size_t)NI * 42 * 42 * 64;
    const size_t P2   = (size_t)NI * 21 * 21 * 64;
    const size_t P3   = (size_t)NI * 10 * 10 * 64;
    const size_t PERG = (P1 + P2 + P3) / 2 + 21u * 32 * 128 + 128;
    const size_t FIXED = 1280000 + 2 * 102400 + 51200 + 320 + 73728 + 1638400;

    const int cands[14] = {25, 20, 18, 16, 14, 12, 10, 8, 6, 5, 4, 3, 2, 1};
    int C = 0;
    for (int t = 0; t < 14; ++t) {
        int c = cands[t];
        if (((size_t)c * PERG + FIXED) * sizeof(float) <= ws_size) { C = c; break; }
    }
    if (C == 0) {
        sentinel_kernel<<<1, 64, 0, stream>>>(out);
        return;
    }

    float* W = (float*)d_ws;
    size_t off = 0;
    unsigned short* pool1h = (unsigned short*)(W + off); off += (size_t)C * P1 / 2;
    unsigned short* pool2h = (unsigned short*)(W + off); off += (size_t)C * P2 / 2;
    unsigned short* pool3h = (unsigned short*)(W + off); off += (size_t)C * P3 / 2;
    float* emb   = W + off; off += 1280000;
    float* part  = W + off; off += 21u * (size_t)C * 32 * 128;
    float* bnp   = W + off; off += (size_t)C * 128;
    unsigned short* w16t = (unsigned short*)(W + off); off += 73728;
    float* xwpart = W + off; off += 1638400;
    float* xwf   = W + off; off += 102400;
    float* xwb   = W + off; off += 102400;
    float* Hs    = W + off; off += 51200;
    float* ceb   = W + off; off += 160;
    float* eqb   = W + off; off += 160;

    // weights -> f16 transposed, once
    for (int l = 1; l < 4; ++l)
        wcvt_kernel<<<9, 256, 0, stream>>>(k[l], w16t + (size_t)l * 9 * 4096);

    for (int g0 = 0; g0 < NG; g0 += C) {
        int ngc = (NG - g0 < C) ? (NG - g0) : C;
        int gx = ngc * 32;

        // L1: f16-MFMA conv3 + stats + in-reg pool -> pool1h (f16 pre-BN); BN in place
        conv3m_kernel<<<dim3(gx, 11), 256, 0, stream>>>(xs, xq, k[0], pool1h, part, g0);
        bn_finalize_kernel<<<dim3(ngc, 64), 256, 0, stream>>>(part, ga[0], be[0], bnp, 1.f / (32.f * 84 * 84), 11, gx);
        bnapplyh_ip_kernel<<<(gx * 42 * 42 * 16 + 255) / 256, 256, 0, stream>>>(pool1h, bnp, 42 * 42, gx * 42 * 42 * 16);

        // L2: halo f16-MFMA conv(42) -> pool2h (f16 pre-BN); BN in place
        conv64m_kernel<42, unsigned short><<<dim3(gx, 18), 256, 0, stream>>>(pool1h, w16t + 9 * 4096, pool2h, part);
        bn_finalize_kernel<<<dim3(ngc, 64), 256, 0, stream>>>(part, ga[1], be[1], bnp, 1.f / (32.f * 42 * 42), 18, gx);
        bnapplyh_ip_kernel<<<(gx * 21 * 21 * 16 + 255) / 256, 256, 0, stream>>>(pool2h, bnp, 21 * 21, gx * 21 * 21 * 16);

        // L3: halo f16-MFMA conv(21) -> pool3h (f16 pre-BN); BN in place
        conv64m_kernel<21, unsigned short><<<dim3(gx, 6), 256, 0, stream>>>(pool2h, w16t + 2 * 9 * 4096, pool3h, part);
        bn_finalize_kernel<<<dim3(ngc, 64), 256, 0, stream>>>(part, ga[2], be[2], bnp, 1.f / (32.f * 21 * 21), 6, gx);
        bnapplyh_ip_kernel<<<(gx * 100 * 16 + 255) / 256, 256, 0, stream>>>(pool3h, bnp, 100, gx * 100 * 16);

        // L4: halo f16-MFMA conv(10) -> emb slice (f32 pre-BN); BN in place
        conv64m_kernel<10, float><<<dim3(gx, 2), 256, 0, stream>>>(pool3h, w16t + 3 * 9 * 4096, emb + (size_t)g0 * 32 * 1600, part);
        bn_finalize_kernel<<<dim3(ngc, 64), 256, 0, stream>>>(part, ga[3], be[3], bnp, 1.f / (32.f * 100), 2, gx);
        bnapply_kernel<<<(gx * 25 * 16 + 255) / 256, 256, 0, stream>>>(emb + (size_t)g0 * 32 * 1600, bnp, 25, gx * 25 * 16);
    }

    // xw projection (split-K GEMM) + reduce
    xw2_kernel<<<dim3(50, 8), 256, 0, stream>>>(emb, fk, bk, xwpart);
    xwred_kernel<<<800, 256, 0, stream>>>(xwpart, xwf, xwb);

    lstm_kernel<<<dim3(NG, 2), 64, 0, stream>>>(xwf, xwb, fr, fb, br, bb, Hs);
    sim_kernel<<<dim3(5, 32), 64, 0, stream>>>(Hs, ysup, yq, ceb, eqb);
    final_kernel<<<1, 64, 0, stream>>>(ceb, eqb, out);
}

// Round 21
// 561.680 us; speedup vs baseline: 2.9310x; 2.9310x over previous
//
#include <hip/hip_runtime.h>
#include <hip/hip_bf16.h>

// ---------------------------------------------------------------------------
// MatchingNetwork forward. Conv trunk fully f16-MFMA (f32 accumulate).
// R21: halo conv64m (R20, correct coverage) with the B-fragment spill fixed:
// B loaded per-tap inside a ROLLED loop (2 live frags, 8 VGPR) from the
// L2-resident w16t instead of 18 register-resident frags (72 VGPR -> scratch,
// R20: 4GB/dispatch scratch traffic). One barrier, in-register stats+pool.
// Activations: [g*32+i][h][w][c], c=64 contiguous.
// ---------------------------------------------------------------------------

#define NG 25
#define NI 32

typedef _Float16 half8v __attribute__((ext_vector_type(8)));
typedef __attribute__((ext_vector_type(4))) float float4v;

__device__ __forceinline__ unsigned short f2h(float f) {
    _Float16 h = (_Float16)f;   // RNE
    union { _Float16 h; unsigned short u; } cv; cv.h = h;
    return cv.u;
}
__device__ __forceinline__ float h2f(unsigned short u) {
    union { unsigned short u; _Float16 h; } cv; cv.u = u;
    return (float)cv.h;
}

__device__ __forceinline__ float fsigm(float x) {
    return __builtin_amdgcn_rcpf(1.f + exp2f(-1.44269504f * x));
}
__device__ __forceinline__ float ftanh(float x) {
    return 1.f - 2.f * __builtin_amdgcn_rcpf(1.f + exp2f(2.88539008f * x));
}

__device__ __forceinline__ void pstore(float* p, size_t off, float v) { p[off] = v; }
__device__ __forceinline__ void pstore(unsigned short* p, size_t off, float v) { p[off] = f2h(v); }

// ---------------- weights f32 [tap][ci][co] -> f16 transposed [tap][co][ci] -
__global__ __launch_bounds__(256)
void wcvt_kernel(const float* __restrict__ wk, unsigned short* __restrict__ w16t) {
    int tap = blockIdx.x;
    for (int e = threadIdx.x; e < 4096; e += 256) {
        int co = e >> 6, ci = e & 63;
        w16t[(size_t)tap * 4096 + e] = f2h(wk[(size_t)tap * 4096 + ci * 64 + co]);
    }
}

// ---------------- Layer 1: f16 MFMA conv(CIN=3) + stats + in-reg pool -------
__global__ __launch_bounds__(256)
void conv3m_kernel(const float* __restrict__ xs, const float* __restrict__ xq,
                   const float* __restrict__ wk, unsigned short* __restrict__ pool1h,
                   float* __restrict__ part, int g0) {
    __shared__ _Float16 sIn[10][304];   // [.][294..303] guaranteed zeros
    __shared__ float sred[4][2][64];
    int gi = blockIdx.x;
    int gl = gi >> 5, i = gi & 31;
    int g = g0 + gl;
    int band = blockIdx.y;
    const float* base = (g < 20) ? xs + (size_t)(i * 20 + g) * (84 * 84 * 3)
                                 : xq + (size_t)(i * 5 + (g - 20)) * (84 * 84 * 3);
    int r0 = band * 8;
    for (int p = threadIdx.x; p < 10 * 152; p += 256) {
        int rr = p / 152, ep = (p - rr * 152) * 2;
        int r = r0 - 1 + rr;
        float v0 = 0.f, v1 = 0.f;
        if (ep < 294 && (unsigned)r < 84u) {
            int col0 = ep / 3 - 1, ci0 = ep - (ep / 3) * 3;
            if ((unsigned)col0 < 84u) v0 = base[((size_t)r * 84 + col0) * 3 + ci0];
            int e1 = ep + 1;
            if (e1 < 294) {
                int col1 = e1 / 3 - 1, ci1 = e1 - (e1 / 3) * 3;
                if ((unsigned)col1 < 84u) v1 = base[((size_t)r * 84 + col1) * 3 + ci1];
            }
        }
        unsigned int pk = (unsigned int)f2h(v0) | ((unsigned int)f2h(v1) << 16);
        ((unsigned int*)&sIn[rr][0])[p - rr * 152] = pk;
    }
    int lane = threadIdx.x & 63;
    int wv = threadIdx.x >> 6;
    int gq = lane >> 4;
    int l16 = lane & 15;
    int rowo[8], eo[8]; bool kv[8];
    #pragma unroll
    for (int j = 0; j < 8; ++j) {
        int k = 8 * gq + j;
        kv[j] = (k < 27);
        int kk = kv[j] ? k : 0;
        int kh = kk / 9; int rem = kk - kh * 9; int kw = rem / 3; int ci = rem - kw * 3;
        rowo[j] = kv[j] ? kh : 0;
        eo[j] = kw * 3 + ci;
    }
    half8v bfr[4];
    #pragma unroll
    for (int ct = 0; ct < 4; ++ct)
        #pragma unroll
        for (int j = 0; j < 8; ++j) {
            int k = 8 * gq + j;
            float w = (k < 27) ? wk[(size_t)k * 64 + ct * 16 + l16] : 0.f;
            bfr[ct][j] = (_Float16)w;
        }
    __syncthreads();

    bool rowv = (r0 + 2 * wv) < 84;
    int prow = band * 4 + wv;
    int sr = 2 * wv;
    float sA[4] = {0.f, 0.f, 0.f, 0.f}, sB[4] = {0.f, 0.f, 0.f, 0.f};

    #pragma unroll 1
    for (int tile = 0; tile < 6; ++tile) {
        int c0 = tile * 16;
        int w = c0 + l16;
        int eoff[8];
        #pragma unroll
        for (int j = 0; j < 8; ++j) eoff[j] = kv[j] ? (w * 3 + eo[j]) : 294;
        float4v acc0[4], acc1[4];
        #pragma unroll
        for (int ct = 0; ct < 4; ++ct) {
            acc0[ct] = (float4v){0.f, 0.f, 0.f, 0.f};
            acc1[ct] = (float4v){0.f, 0.f, 0.f, 0.f};
        }
        #pragma unroll
        for (int rs = 0; rs < 2; ++rs) {
            half8v af;
            #pragma unroll
            for (int j = 0; j < 8; ++j)
                af[j] = sIn[sr + rs + rowo[j]][eoff[j]];
            if (rs == 0) {
                #pragma unroll
                for (int ct = 0; ct < 4; ++ct)
                    acc0[ct] = __builtin_amdgcn_mfma_f32_16x16x32_f16(af, bfr[ct], acc0[ct], 0, 0, 0);
            } else {
                #pragma unroll
                for (int ct = 0; ct < 4; ++ct)
                    acc1[ct] = __builtin_amdgcn_mfma_f32_16x16x32_f16(af, bfr[ct], acc1[ct], 0, 0, 0);
            }
        }
        #pragma unroll
        for (int ct = 0; ct < 4; ++ct) {
            #pragma unroll
            for (int r = 0; r < 4; ++r) {
                float a0 = acc0[ct][r], a1 = acc1[ct][r];
                sA[ct] += a0 + a1;
                sB[ct] = fmaf(a0, a0, fmaf(a1, a1, sB[ct]));
            }
            if (rowv) {
                float m01 = fmaxf(fmaxf(acc0[ct][0], acc0[ct][1]),
                                  fmaxf(acc1[ct][0], acc1[ct][1]));
                float m23 = fmaxf(fmaxf(acc0[ct][2], acc0[ct][3]),
                                  fmaxf(acc1[ct][2], acc1[ct][3]));
                int pc0 = (c0 + gq * 4) >> 1;
                size_t rowbase = (((size_t)gi * 42 + prow) * 42) * 64 + ct * 16 + l16;
                if (pc0 < 42)     pool1h[rowbase + (size_t)pc0 * 64] = f2h(m01);
                if (pc0 + 1 < 42) pool1h[rowbase + (size_t)(pc0 + 1) * 64] = f2h(m23);
            }
        }
    }
    #pragma unroll
    for (int ct = 0; ct < 4; ++ct) {
        float s = sA[ct], q = sB[ct];
        s += __shfl_xor(s, 16); s += __shfl_xor(s, 32);
        q += __shfl_xor(q, 16); q += __shfl_xor(q, 32);
        if (gq == 0) { sred[wv][0][ct * 16 + l16] = s; sred[wv][1][ct * 16 + l16] = q; }
    }
    __syncthreads();
    if (threadIdx.x < 64) {
        int co = threadIdx.x;
        float s = sred[0][0][co] + sred[1][0][co] + sred[2][0][co] + sred[3][0][co];
        float q = sred[0][1][co] + sred[1][1][co] + sred[2][1][co] + sred[3][1][co];
        size_t pr = (size_t)blockIdx.y * gridDim.x + blockIdx.x;
        part[pr * 128 + co] = s;
        part[pr * 128 + 64 + co] = q;
    }
}

// ---------------- Layers 2-4: halo-tile f16 MFMA conv + stats + pool --------
// Block = 4 waves; tile 8 rows x 16 cols = 128 positions x 64 co. Halo
// [10][18][64] f16 staged once; ONE barrier. B fragments loaded PER TAP from
// L2-resident w16t inside a rolled loop (2 live frags -> no spill; R20/R21).
template<int D, typename OutT>
__global__ __launch_bounds__(256, 4)
void conv64m_kernel(const unsigned short* __restrict__ act16,
                    const unsigned short* __restrict__ w16t,
                    OutT* __restrict__ poolout, float* __restrict__ part) {
    constexpr int nCT = (D + 15) / 16;
    constexpr int PD = D / 2;
    __shared__ __align__(16) unsigned short sH[10 * 18 * 72];  // 25,920 B
    int gi = blockIdx.x;
    int rt = blockIdx.y / nCT, ctile = blockIdx.y % nCT;
    int r0 = rt * 8, c0 = ctile * 16;
    const unsigned short* in = act16 + (size_t)gi * D * D * 64;

    int lane = threadIdx.x & 63;
    int wv = threadIdx.x >> 6;
    int gq = lane >> 4;
    int l16 = lane & 15;

    // stage halo tile: rows r0-1..r0+8, cols c0-1..c0+16, 64 ci (zeros OOB)
    for (int s = threadIdx.x; s < 10 * 18 * 8; s += 256) {
        int row = s / 144, rem = s - row * 144;
        int col = rem >> 3, q = rem & 7;
        int h = r0 + row - 1, w = c0 + col - 1;
        uint4 v = {0, 0, 0, 0};
        if ((unsigned)h < (unsigned)D && (unsigned)w < (unsigned)D)
            v = *(const uint4*)&in[((size_t)h * D + w) * 64 + q * 8];
        *(uint4*)&sH[row * 1296 + col * 72 + q * 8] = v;
    }
    __syncthreads();

    float4v acc[8];
    #pragma unroll
    for (int m = 0; m < 8; ++m) acc[m] = (float4v){0.f, 0.f, 0.f, 0.f};

    const unsigned short* wbase = w16t + ((size_t)(wv * 16 + l16)) * 64 + gq * 8;
    int abase = l16 * 72 + gq * 8;

    #pragma unroll 1
    for (int tap = 0; tap < 9; ++tap) {
        int kh = tap / 3;
        int kw = tap - kh * 3;
        // B fragments for this tap only (8 VGPR live)
        half8v b0 = *(const half8v*)(wbase + (size_t)tap * 4096);
        half8v b1 = *(const half8v*)(wbase + (size_t)tap * 4096 + 32);
        int hb = kh * 1296 + kw * 72 + abase;
        #pragma unroll
        for (int m = 0; m < 8; ++m) {
            half8v a0 = *(const half8v*)&sH[m * 1296 + hb];
            half8v a1 = *(const half8v*)&sH[m * 1296 + hb + 32];
            acc[m] = __builtin_amdgcn_mfma_f32_16x16x32_f16(a0, b0, acc[m], 0, 0, 0);
            acc[m] = __builtin_amdgcn_mfma_f32_16x16x32_f16(a1, b1, acc[m], 0, 0, 0);
        }
    }

    // stats: lane's co = wv*16+l16; sum over 8 m x 4 r; reduce over gq groups
    {
        float s = 0.f, s2 = 0.f;
        #pragma unroll
        for (int m = 0; m < 8; ++m)
            #pragma unroll
            for (int r = 0; r < 4; ++r) {
                float a = acc[m][r];
                s += a; s2 = fmaf(a, a, s2);
            }
        s += __shfl_xor(s, 16); s += __shfl_xor(s, 32);
        s2 += __shfl_xor(s2, 16); s2 += __shfl_xor(s2, 32);
        if (gq == 0) {
            size_t prow = (size_t)blockIdx.y * gridDim.x + blockIdx.x;
            part[prow * 128 + wv * 16 + l16] = s;
            part[prow * 128 + 64 + wv * 16 + l16] = s2;
        }
    }
    // in-register 2x2 pool. acc[m][r] = conv(row r0+m, col c0+gq*4+r), co=wv*16+l16.
    int ch = wv * 16 + l16;
    #pragma unroll
    for (int p = 0; p < 4; ++p) {
        float m01 = fmaxf(fmaxf(acc[2 * p][0], acc[2 * p][1]),
                          fmaxf(acc[2 * p + 1][0], acc[2 * p + 1][1]));
        float m23 = fmaxf(fmaxf(acc[2 * p][2], acc[2 * p][3]),
                          fmaxf(acc[2 * p + 1][2], acc[2 * p + 1][3]));
        int gpr = rt * 4 + p;
        int gpc0 = ctile * 8 + gq * 2;
        if (gpr < PD) {
            size_t rb = (((size_t)gi * PD + gpr) * PD) * 64 + ch;
            if (gpc0 < PD)     pstore(poolout, rb + (size_t)gpc0 * 64, m01);
            if (gpc0 + 1 < PD) pstore(poolout, rb + (size_t)(gpc0 + 1) * 64, m23);
        }
    }
}

// bn_finalize: one (group, channel) per block. grid (ngc, 64).
__global__ __launch_bounds__(256)
void bn_finalize_kernel(const float* __restrict__ part,
                        const float* __restrict__ gamma,
                        const float* __restrict__ beta,
                        float* __restrict__ bnp, float invN, int nby, int gridx) {
    int g = blockIdx.x;
    int c = blockIdx.y;
    int nrows = nby * 32;
    float s = 0.f, s2 = 0.f;
    for (int rr = threadIdx.x; rr < nrows; rr += 256) {
        int by = rr >> 5, i = rr & 31;
        size_t row = (size_t)by * gridx + g * 32 + i;
        s  += part[row * 128 + c];
        s2 += part[row * 128 + 64 + c];
    }
    __shared__ float red[2][256];
    red[0][threadIdx.x] = s; red[1][threadIdx.x] = s2;
    __syncthreads();
    #pragma unroll
    for (int o = 128; o > 0; o >>= 1) {
        if (threadIdx.x < o) {
            red[0][threadIdx.x] += red[0][threadIdx.x + o];
            red[1][threadIdx.x] += red[1][threadIdx.x + o];
        }
        __syncthreads();
    }
    if (threadIdx.x == 0) {
        s = red[0][0]; s2 = red[1][0];
        float mean = s * invN;
        float var  = s2 * invN - mean * mean;
        float sc = gamma[c] * rsqrtf(var + 1e-3f);
        bnp[g * 128 + c] = sc;
        bnp[g * 128 + 64 + c] = beta[c] - sc * mean;
    }
}

// BN+ReLU in place on f16 buffer (L1/L2/L3 paths).
__global__ __launch_bounds__(256)
void bnapplyh_ip_kernel(unsigned short* __restrict__ buf, const float* __restrict__ bnp,
                        int PP, int total) {
    int v = blockIdx.x * 256 + threadIdx.x;
    if (v >= total) return;
    int c4 = (v & 15) * 4;
    int pos = v >> 4;
    int gi = pos / PP;
    int gl = gi >> 5;
    float4 sc = *(const float4*)&bnp[gl * 128 + c4];
    float4 sh = *(const float4*)&bnp[gl * 128 + 64 + c4];
    ushort4 x = *(const ushort4*)&buf[(size_t)pos * 64 + c4];
    ushort4 o;
    o.x = f2h(fmaxf(0.f, fmaf(sc.x, h2f(x.x), sh.x)));
    o.y = f2h(fmaxf(0.f, fmaf(sc.y, h2f(x.y), sh.y)));
    o.z = f2h(fmaxf(0.f, fmaf(sc.z, h2f(x.z), sh.z)));
    o.w = f2h(fmaxf(0.f, fmaf(sc.w, h2f(x.w), sh.w)));
    *(ushort4*)&buf[(size_t)pos * 64 + c4] = o;
}

// In-place f32 BN+ReLU (L4 emb path only).
__global__ __launch_bounds__(256)
void bnapply_kernel(float* __restrict__ buf, const float* __restrict__ bnp,
                    int PP, int total) {
    int v = blockIdx.x * 256 + threadIdx.x;
    if (v >= total) return;
    int c4 = (v & 15) * 4;
    int pos = v >> 4;
    int gi = pos / PP;
    int gl = gi >> 5;
    float4 sc = *(const float4*)&bnp[gl * 128 + c4];
    float4 sh = *(const float4*)&bnp[gl * 128 + 64 + c4];
    float4 x = *(const float4*)&buf[(size_t)pos * 64 + c4];
    float4 o;
    o.x = fmaxf(0.f, fmaf(sc.x, x.x, sh.x));
    o.y = fmaxf(0.f, fmaf(sc.y, x.y, sh.y));
    o.z = fmaxf(0.f, fmaf(sc.z, x.z, sh.z));
    o.w = fmaxf(0.f, fmaf(sc.w, x.w, sh.w));
    *(float4*)&buf[(size_t)pos * 64 + c4] = o;
}

// ---------------- xw projection: tiled split-K f32 GEMM ---------------------
__global__ __launch_bounds__(256)
void xw2_kernel(const float* __restrict__ emb, const float* __restrict__ fk,
                const float* __restrict__ bk, float* __restrict__ xwpart) {
    __shared__ float se[16][200];
    int rt = blockIdx.x;
    int kb = blockIdx.y;
    for (int idx = threadIdx.x; idx < 16 * 200; idx += 256) {
        int r = idx / 200, kk = idx - (idx / 200) * 200;
        se[r][kk] = emb[(size_t)(rt * 16 + r) * 1600 + kb * 200 + kk];
    }
    __syncthreads();
    int j = threadIdx.x & 127;
    int half = threadIdx.x >> 7;
    const float* Wm = half ? bk : fk;
    float acc[16];
    #pragma unroll
    for (int r = 0; r < 16; ++r) acc[r] = 0.f;
    for (int kk = 0; kk < 200; ++kk) {
        float w = Wm[(size_t)(kb * 200 + kk) * 128 + j];
        #pragma unroll
        for (int r = 0; r < 16; ++r) acc[r] = fmaf(se[r][kk], w, acc[r]);
    }
    #pragma unroll
    for (int r = 0; r < 16; ++r)
        xwpart[((size_t)kb * 800 + rt * 16 + r) * 256 + half * 128 + j] = acc[r];
}

__global__ __launch_bounds__(256)
void xwred_kernel(const float* __restrict__ xwpart, float* __restrict__ xwf,
                  float* __restrict__ xwb) {
    int gi = blockIdx.x;
    int c = threadIdx.x;
    float s = 0.f;
    #pragma unroll
    for (int kb = 0; kb < 8; ++kb)
        s += xwpart[((size_t)kb * 800 + gi) * 256 + c];
    if (c < 128) xwf[(size_t)gi * 128 + c] = s;
    else         xwb[(size_t)gi * 128 + (c - 128)] = s;
}

// ---------------- LSTM: latency-optimized, all state in registers -----------
__global__ __launch_bounds__(64, 1)
void lstm_kernel(const float* __restrict__ xwf, const float* __restrict__ xwb,
                 const float* __restrict__ fr, const float* __restrict__ fb,
                 const float* __restrict__ br, const float* __restrict__ bb,
                 float* __restrict__ Hs) {
    int g = blockIdx.x;
    int dir = blockIdx.y;
    int j = threadIdx.x;
    const float* xw = dir ? xwb : xwf;
    const float* Wr = dir ? br : fr;
    const float* bv = dir ? bb : fb;
    float frA[32], frB[32];
    #pragma unroll
    for (int k = 0; k < 32; ++k) {
        frA[k] = Wr[k * 128 + j];
        frB[k] = Wr[k * 128 + 64 + j];
    }
    float bA = bv[j], bB = bv[64 + j];
    float xA[32], xB[32];
    #pragma unroll
    for (int st = 0; st < 32; ++st) {
        int t = dir ? (31 - st) : st;
        xA[st] = xw[((size_t)g * NI + t) * 128 + j];
        xB[st] = xw[((size_t)g * NI + t) * 128 + 64 + j];
    }
    float h = 0.f, c = 0.f;
    #pragma unroll
    for (int st = 0; st < 32; ++st) {
        int t = dir ? (31 - st) : st;
        float a0 = xA[st] + bA, a1 = 0.f, a2 = 0.f, a3 = 0.f;
        float b0 = xB[st] + bB, b1 = 0.f, b2 = 0.f, b3 = 0.f;
        #pragma unroll
        for (int kk = 0; kk < 8; ++kk) {
            float h0 = __shfl(h, kk);
            float h1 = __shfl(h, kk + 8);
            float h2 = __shfl(h, kk + 16);
            float h3 = __shfl(h, kk + 24);
            a0 = fmaf(h0, frA[kk], a0);      b0 = fmaf(h0, frB[kk], b0);
            a1 = fmaf(h1, frA[kk + 8], a1);  b1 = fmaf(h1, frB[kk + 8], b1);
            a2 = fmaf(h2, frA[kk + 16], a2); b2 = fmaf(h2, frB[kk + 16], b2);
            a3 = fmaf(h3, frA[kk + 24], a3); b3 = fmaf(h3, frB[kk + 24], b3);
        }
        float accA = (a0 + a1) + (a2 + a3);
        float accB = (b0 + b1) + (b2 + b3);
        float ig = accA;
        float gg = accB;
        float fg = __shfl(accA, (j & 31) + 32);
        float og = __shfl(accB, (j & 31) + 32);
        float cn = fsigm(fg) * c + fsigm(ig) * ftanh(gg);
        float hn = fsigm(og) * ftanh(cn);
        if (j < 32) {
            c = cn; h = hn;
            Hs[((size_t)g * NI + t) * 64 + dir * 32 + j] = hn;
        }
    }
}

__global__ __launch_bounds__(64, 1)
void sim_kernel(const float* __restrict__ Hs, const int* __restrict__ ysup,
                const int* __restrict__ yq, float* __restrict__ ceb,
                float* __restrict__ eqb) {
    int q = blockIdx.x;
    int i = blockIdx.y;
    int lane = threadIdx.x;
    float qv = Hs[((size_t)(20 + q) * NI + i) * 64 + lane];
    float ls[20];
    for (int s = 0; s < 20; ++s) {
        float sv = Hs[((size_t)s * NI + i) * 64 + lane];
        float d = qv * sv;
        float m = sv * sv;
        #pragma unroll
        for (int o = 32; o > 0; o >>= 1) {
            d += __shfl_xor(d, o);
            m += __shfl_xor(m, o);
        }
        ls[s] = d * rsqrtf(fmaxf(m, 1e-10f));
    }
    if (lane == 0) {
        float mx = -1e30f;
        for (int s = 0; s < 20; ++s) mx = fmaxf(mx, ls[s]);
        float sum = 0.f, sim[20];
        for (int s = 0; s < 20; ++s) { sim[s] = expf(ls[s] - mx); sum += sim[s]; }
        float inv = 1.f / sum;
        float preds[20];
        for (int w = 0; w < 20; ++w) preds[w] = 0.f;
        for (int s = 0; s < 20; ++s) preds[ysup[i * 20 + s]] += sim[s] * inv;
        int y = yq[i * 5 + q];
        float pv = fminf(fmaxf(preds[y], 1e-7f), 1.f - 1e-7f);
        ceb[q * NI + i] = -logf(pv);
        int am = 0; float bm = preds[0];
        for (int w = 1; w < 20; ++w) if (preds[w] > bm) { bm = preds[w]; am = w; }
        eqb[q * NI + i] = (am == y) ? 1.f : 0.f;
    }
}

__global__ __launch_bounds__(64, 1)
void final_kernel(const float* __restrict__ ceb, const float* __restrict__ eqb,
                  float* __restrict__ out) {
    int lane = threadIdx.x;
    float e = 0.f;
    if (lane < 32) {
        float ce = 0.f;
        for (int q = 0; q < 5; ++q) { ce += ceb[q * NI + lane]; e += eqb[q * NI + lane]; }
        out[lane] = ce * 0.2f;
    }
    #pragma unroll
    for (int o = 32; o > 0; o >>= 1) e += __shfl_xor(e, o);
    if (lane == 0) out[32] = e / 160.f;
}

__global__ void sentinel_kernel(float* out) {
    if (threadIdx.x < 33) out[threadIdx.x] = -777.25f;
}

extern "C" void kernel_launch(void* const* d_in, const int* in_sizes, int n_in,
                              void* d_out, int out_size, void* d_ws, size_t ws_size,
                              hipStream_t stream) {
    const float* xs   = (const float*)d_in[0];
    const int*   ysup = (const int*)  d_in[1];
    const float* xq   = (const float*)d_in[2];
    const int*   yq   = (const int*)  d_in[3];
    const float* k[4]  = { (const float*)d_in[4],  (const float*)d_in[8],
                           (const float*)d_in[12], (const float*)d_in[16] };
    const float* ga[4] = { (const float*)d_in[6],  (const float*)d_in[10],
                           (const float*)d_in[14], (const float*)d_in[18] };
    const float* be[4] = { (const float*)d_in[7],  (const float*)d_in[11],
                           (const float*)d_in[15], (const float*)d_in[19] };
    const float* fk = (const float*)d_in[20];
    const float* fr = (const float*)d_in[21];
    const float* fb = (const float*)d_in[22];
    const float* bk = (const float*)d_in[23];
    const float* br = (const float*)d_in[24];
    const float* bb = (const float*)d_in[25];
    float* out = (float*)d_out;

    // per-group float-slot counts (all pools are f16 now)
    const size_t P1   = (size_t)NI * 42 * 42 * 64;
    const size_t P2   = (size_t)NI * 21 * 21 * 64;
    const size_t P3   = (size_t)NI * 10 * 10 * 64;
    const size_t PERG = (P1 + P2 + P3) / 2 + 21u * 32 * 128 + 128;
    const size_t FIXED = 1280000 + 2 * 102400 + 51200 + 320 + 73728 + 1638400;

    const int cands[14] = {25, 20, 18, 16, 14, 12, 10, 8, 6, 5, 4, 3, 2, 1};
    int C = 0;
    for (int t = 0; t < 14; ++t) {
        int c = cands[t];
        if (((size_t)c * PERG + FIXED) * sizeof(float) <= ws_size) { C = c; break; }
    }
    if (C == 0) {
        sentinel_kernel<<<1, 64, 0, stream>>>(out);
        return;
    }

    float* W = (float*)d_ws;
    size_t off = 0;
    unsigned short* pool1h = (unsigned short*)(W + off); off += (size_t)C * P1 / 2;
    unsigned short* pool2h = (unsigned short*)(W + off); off += (size_t)C * P2 / 2;
    unsigned short* pool3h = (unsigned short*)(W + off); off += (size_t)C * P3 / 2;
    float* emb   = W + off; off += 1280000;
    float* part  = W + off; off += 21u * (size_t)C * 32 * 128;
    float* bnp   = W + off; off += (size_t)C * 128;
    unsigned short* w16t = (unsigned short*)(W + off); off += 73728;
    float* xwpart = W + off; off += 1638400;
    float* xwf   = W + off; off += 102400;
    float* xwb   = W + off; off += 102400;
    float* Hs    = W + off; off += 51200;
    float* ceb   = W + off; off += 160;
    float* eqb   = W + off; off += 160;

    // weights -> f16 transposed, once
    for (int l = 1; l < 4; ++l)
        wcvt_kernel<<<9, 256, 0, stream>>>(k[l], w16t + (size_t)l * 9 * 4096);

    for (int g0 = 0; g0 < NG; g0 += C) {
        int ngc = (NG - g0 < C) ? (NG - g0) : C;
        int gx = ngc * 32;

        // L1: f16-MFMA conv3 + stats + in-reg pool -> pool1h (f16 pre-BN); BN in place
        conv3m_kernel<<<dim3(gx, 11), 256, 0, stream>>>(xs, xq, k[0], pool1h, part, g0);
        bn_finalize_kernel<<<dim3(ngc, 64), 256, 0, stream>>>(part, ga[0], be[0], bnp, 1.f / (32.f * 84 * 84), 11, gx);
        bnapplyh_ip_kernel<<<(gx * 42 * 42 * 16 + 255) / 256, 256, 0, stream>>>(pool1h, bnp, 42 * 42, gx * 42 * 42 * 16);

        // L2: halo f16-MFMA conv(42) -> pool2h (f16 pre-BN); BN in place
        conv64m_kernel<42, unsigned short><<<dim3(gx, 18), 256, 0, stream>>>(pool1h, w16t + 9 * 4096, pool2h, part);
        bn_finalize_kernel<<<dim3(ngc, 64), 256, 0, stream>>>(part, ga[1], be[1], bnp, 1.f / (32.f * 42 * 42), 18, gx);
        bnapplyh_ip_kernel<<<(gx * 21 * 21 * 16 + 255) / 256, 256, 0, stream>>>(pool2h, bnp, 21 * 21, gx * 21 * 21 * 16);

        // L3: halo f16-MFMA conv(21) -> pool3h (f16 pre-BN); BN in place
        conv64m_kernel<21, unsigned short><<<dim3(gx, 6), 256, 0, stream>>>(pool2h, w16t + 2 * 9 * 4096, pool3h, part);
        bn_finalize_kernel<<<dim3(ngc, 64), 256, 0, stream>>>(part, ga[2], be[2], bnp, 1.f / (32.f * 21 * 21), 6, gx);
        bnapplyh_ip_kernel<<<(gx * 100 * 16 + 255) / 256, 256, 0, stream>>>(pool3h, bnp, 100, gx * 100 * 16);

        // L4: halo f16-MFMA conv(10) -> emb slice (f32 pre-BN); BN in place
        conv64m_kernel<10, float><<<dim3(gx, 2), 256, 0, stream>>>(pool3h, w16t + 3 * 9 * 4096, emb + (size_t)g0 * 32 * 1600, part);
        bn_finalize_kernel<<<dim3(ngc, 64), 256, 0, stream>>>(part, ga[3], be[3], bnp, 1.f / (32.f * 100), 2, gx);
        bnapply_kernel<<<(gx * 25 * 16 + 255) / 256, 256, 0, stream>>>(emb + (size_t)g0 * 32 * 1600, bnp, 25, gx * 25 * 16);
    }

    // xw projection (split-K GEMM) + reduce
    xw2_kernel<<<dim3(50, 8), 256, 0, stream>>>(emb, fk, bk, xwpart);
    xwred_kernel<<<800, 256, 0, stream>>>(xwpart, xwf, xwb);

    lstm_kernel<<<dim3(NG, 2), 64, 0, stream>>>(xwf, xwb, fr, fb, br, bb, Hs);
    sim_kernel<<<dim3(5, 32), 64, 0, stream>>>(Hs, ysup, yq, ceb, eqb);
    final_kernel<<<1, 64, 0, stream>>>(ceb, eqb, out);
}

// Round 22
// 548.024 us; speedup vs baseline: 3.0040x; 1.0249x over previous
//
#include <hip/hip_runtime.h>
#include <hip/hip_bf16.h>

// ---------------------------------------------------------------------------
// MatchingNetwork forward. Conv trunk fully f16-MFMA (f32 accumulate).
// R22: conv64m inner loop kw-major with A-row reuse: per (kw,ks) load 10 halo
// rows once -> 24 MFMAs per 10 ds_read_b128 (was 1:1; LDS-read-bound at 34%
// MfmaUtil). B (6 frags) loaded once per kw, overlapped by 48 MFMAs.
// Activations: [g*32+i][h][w][c], c=64 contiguous.
// ---------------------------------------------------------------------------

#define NG 25
#define NI 32

typedef _Float16 half8v __attribute__((ext_vector_type(8)));
typedef __attribute__((ext_vector_type(4))) float float4v;

__device__ __forceinline__ unsigned short f2h(float f) {
    _Float16 h = (_Float16)f;   // RNE
    union { _Float16 h; unsigned short u; } cv; cv.h = h;
    return cv.u;
}
__device__ __forceinline__ float h2f(unsigned short u) {
    union { unsigned short u; _Float16 h; } cv; cv.u = u;
    return (float)cv.h;
}

__device__ __forceinline__ float fsigm(float x) {
    return __builtin_amdgcn_rcpf(1.f + exp2f(-1.44269504f * x));
}
__device__ __forceinline__ float ftanh(float x) {
    return 1.f - 2.f * __builtin_amdgcn_rcpf(1.f + exp2f(2.88539008f * x));
}

__device__ __forceinline__ void pstore(float* p, size_t off, float v) { p[off] = v; }
__device__ __forceinline__ void pstore(unsigned short* p, size_t off, float v) { p[off] = f2h(v); }

// ---------------- weights f32 [tap][ci][co] -> f16 transposed [tap][co][ci] -
__global__ __launch_bounds__(256)
void wcvt_kernel(const float* __restrict__ wk, unsigned short* __restrict__ w16t) {
    int tap = blockIdx.x;
    for (int e = threadIdx.x; e < 4096; e += 256) {
        int co = e >> 6, ci = e & 63;
        w16t[(size_t)tap * 4096 + e] = f2h(wk[(size_t)tap * 4096 + ci * 64 + co]);
    }
}

// ---------------- Layer 1: f16 MFMA conv(CIN=3) + stats + in-reg pool -------
__global__ __launch_bounds__(256)
void conv3m_kernel(const float* __restrict__ xs, const float* __restrict__ xq,
                   const float* __restrict__ wk, unsigned short* __restrict__ pool1h,
                   float* __restrict__ part, int g0) {
    __shared__ _Float16 sIn[10][304];   // [.][294..303] guaranteed zeros
    __shared__ float sred[4][2][64];
    int gi = blockIdx.x;
    int gl = gi >> 5, i = gi & 31;
    int g = g0 + gl;
    int band = blockIdx.y;
    const float* base = (g < 20) ? xs + (size_t)(i * 20 + g) * (84 * 84 * 3)
                                 : xq + (size_t)(i * 5 + (g - 20)) * (84 * 84 * 3);
    int r0 = band * 8;
    for (int p = threadIdx.x; p < 10 * 152; p += 256) {
        int rr = p / 152, ep = (p - rr * 152) * 2;
        int r = r0 - 1 + rr;
        float v0 = 0.f, v1 = 0.f;
        if (ep < 294 && (unsigned)r < 84u) {
            int col0 = ep / 3 - 1, ci0 = ep - (ep / 3) * 3;
            if ((unsigned)col0 < 84u) v0 = base[((size_t)r * 84 + col0) * 3 + ci0];
            int e1 = ep + 1;
            if (e1 < 294) {
                int col1 = e1 / 3 - 1, ci1 = e1 - (e1 / 3) * 3;
                if ((unsigned)col1 < 84u) v1 = base[((size_t)r * 84 + col1) * 3 + ci1];
            }
        }
        unsigned int pk = (unsigned int)f2h(v0) | ((unsigned int)f2h(v1) << 16);
        ((unsigned int*)&sIn[rr][0])[p - rr * 152] = pk;
    }
    int lane = threadIdx.x & 63;
    int wv = threadIdx.x >> 6;
    int gq = lane >> 4;
    int l16 = lane & 15;
    int rowo[8], eo[8]; bool kv[8];
    #pragma unroll
    for (int j = 0; j < 8; ++j) {
        int k = 8 * gq + j;
        kv[j] = (k < 27);
        int kk = kv[j] ? k : 0;
        int kh = kk / 9; int rem = kk - kh * 9; int kw = rem / 3; int ci = rem - kw * 3;
        rowo[j] = kv[j] ? kh : 0;
        eo[j] = kw * 3 + ci;
    }
    half8v bfr[4];
    #pragma unroll
    for (int ct = 0; ct < 4; ++ct)
        #pragma unroll
        for (int j = 0; j < 8; ++j) {
            int k = 8 * gq + j;
            float w = (k < 27) ? wk[(size_t)k * 64 + ct * 16 + l16] : 0.f;
            bfr[ct][j] = (_Float16)w;
        }
    __syncthreads();

    bool rowv = (r0 + 2 * wv) < 84;
    int prow = band * 4 + wv;
    int sr = 2 * wv;
    float sA[4] = {0.f, 0.f, 0.f, 0.f}, sB[4] = {0.f, 0.f, 0.f, 0.f};

    #pragma unroll 1
    for (int tile = 0; tile < 6; ++tile) {
        int c0 = tile * 16;
        int w = c0 + l16;
        int eoff[8];
        #pragma unroll
        for (int j = 0; j < 8; ++j) eoff[j] = kv[j] ? (w * 3 + eo[j]) : 294;
        float4v acc0[4], acc1[4];
        #pragma unroll
        for (int ct = 0; ct < 4; ++ct) {
            acc0[ct] = (float4v){0.f, 0.f, 0.f, 0.f};
            acc1[ct] = (float4v){0.f, 0.f, 0.f, 0.f};
        }
        #pragma unroll
        for (int rs = 0; rs < 2; ++rs) {
            half8v af;
            #pragma unroll
            for (int j = 0; j < 8; ++j)
                af[j] = sIn[sr + rs + rowo[j]][eoff[j]];
            if (rs == 0) {
                #pragma unroll
                for (int ct = 0; ct < 4; ++ct)
                    acc0[ct] = __builtin_amdgcn_mfma_f32_16x16x32_f16(af, bfr[ct], acc0[ct], 0, 0, 0);
            } else {
                #pragma unroll
                for (int ct = 0; ct < 4; ++ct)
                    acc1[ct] = __builtin_amdgcn_mfma_f32_16x16x32_f16(af, bfr[ct], acc1[ct], 0, 0, 0);
            }
        }
        #pragma unroll
        for (int ct = 0; ct < 4; ++ct) {
            #pragma unroll
            for (int r = 0; r < 4; ++r) {
                float a0 = acc0[ct][r], a1 = acc1[ct][r];
                sA[ct] += a0 + a1;
                sB[ct] = fmaf(a0, a0, fmaf(a1, a1, sB[ct]));
            }
            if (rowv) {
                float m01 = fmaxf(fmaxf(acc0[ct][0], acc0[ct][1]),
                                  fmaxf(acc1[ct][0], acc1[ct][1]));
                float m23 = fmaxf(fmaxf(acc0[ct][2], acc0[ct][3]),
                                  fmaxf(acc1[ct][2], acc1[ct][3]));
                int pc0 = (c0 + gq * 4) >> 1;
                size_t rowbase = (((size_t)gi * 42 + prow) * 42) * 64 + ct * 16 + l16;
                if (pc0 < 42)     pool1h[rowbase + (size_t)pc0 * 64] = f2h(m01);
                if (pc0 + 1 < 42) pool1h[rowbase + (size_t)(pc0 + 1) * 64] = f2h(m23);
            }
        }
    }
    #pragma unroll
    for (int ct = 0; ct < 4; ++ct) {
        float s = sA[ct], q = sB[ct];
        s += __shfl_xor(s, 16); s += __shfl_xor(s, 32);
        q += __shfl_xor(q, 16); q += __shfl_xor(q, 32);
        if (gq == 0) { sred[wv][0][ct * 16 + l16] = s; sred[wv][1][ct * 16 + l16] = q; }
    }
    __syncthreads();
    if (threadIdx.x < 64) {
        int co = threadIdx.x;
        float s = sred[0][0][co] + sred[1][0][co] + sred[2][0][co] + sred[3][0][co];
        float q = sred[0][1][co] + sred[1][1][co] + sred[2][1][co] + sred[3][1][co];
        size_t pr = (size_t)blockIdx.y * gridDim.x + blockIdx.x;
        part[pr * 128 + co] = s;
        part[pr * 128 + 64 + co] = q;
    }
}

// ---------------- Layers 2-4: halo-tile f16 MFMA conv + stats + pool --------
// Block = 4 waves; tile 8 rows x 16 cols x 64 co. Halo [10][18][64] f16
// staged once, ONE barrier. kw-major inner loop: per (kw,ks) 10 A-row reads
// feed 24 MFMAs (2.4x fewer LDS reads than tap-major); 6 B frags per kw.
template<int D, typename OutT>
__global__ __launch_bounds__(256, 4)
void conv64m_kernel(const unsigned short* __restrict__ act16,
                    const unsigned short* __restrict__ w16t,
                    OutT* __restrict__ poolout, float* __restrict__ part) {
    constexpr int nCT = (D + 15) / 16;
    constexpr int PD = D / 2;
    __shared__ __align__(16) unsigned short sH[10 * 18 * 72];  // 25,920 B
    int gi = blockIdx.x;
    int rt = blockIdx.y / nCT, ctile = blockIdx.y % nCT;
    int r0 = rt * 8, c0 = ctile * 16;
    const unsigned short* in = act16 + (size_t)gi * D * D * 64;

    int lane = threadIdx.x & 63;
    int wv = threadIdx.x >> 6;
    int gq = lane >> 4;
    int l16 = lane & 15;

    // stage halo tile: rows r0-1..r0+8, cols c0-1..c0+16, 64 ci (zeros OOB)
    for (int s = threadIdx.x; s < 10 * 18 * 8; s += 256) {
        int row = s / 144, rem = s - row * 144;
        int col = rem >> 3, q = rem & 7;
        int h = r0 + row - 1, w = c0 + col - 1;
        uint4 v = {0, 0, 0, 0};
        if ((unsigned)h < (unsigned)D && (unsigned)w < (unsigned)D)
            v = *(const uint4*)&in[((size_t)h * D + w) * 64 + q * 8];
        *(uint4*)&sH[row * 1296 + col * 72 + q * 8] = v;
    }
    __syncthreads();

    float4v acc[8];
    #pragma unroll
    for (int m = 0; m < 8; ++m) acc[m] = (float4v){0.f, 0.f, 0.f, 0.f};

    const unsigned short* wbase = w16t + ((size_t)(wv * 16 + l16)) * 64 + gq * 8;

    #pragma unroll 1
    for (int kw = 0; kw < 3; ++kw) {
        // B fragments for this column: 3 kh x 2 ks (24 VGPR)
        half8v B00 = *(const half8v*)(wbase + (size_t)(0 * 3 + kw) * 4096);
        half8v B01 = *(const half8v*)(wbase + (size_t)(0 * 3 + kw) * 4096 + 32);
        half8v B10 = *(const half8v*)(wbase + (size_t)(1 * 3 + kw) * 4096);
        half8v B11 = *(const half8v*)(wbase + (size_t)(1 * 3 + kw) * 4096 + 32);
        half8v B20 = *(const half8v*)(wbase + (size_t)(2 * 3 + kw) * 4096);
        half8v B21 = *(const half8v*)(wbase + (size_t)(2 * 3 + kw) * 4096 + 32);
        int cb = (l16 + kw) * 72 + gq * 8;
        #pragma unroll
        for (int ks = 0; ks < 2; ++ks) {
            // 10 halo rows at this (col, ks): serve kh=0..2 for all m
            half8v A0 = *(const half8v*)&sH[0 * 1296 + cb + ks * 32];
            half8v A1 = *(const half8v*)&sH[1 * 1296 + cb + ks * 32];
            half8v A2 = *(const half8v*)&sH[2 * 1296 + cb + ks * 32];
            half8v A3 = *(const half8v*)&sH[3 * 1296 + cb + ks * 32];
            half8v A4 = *(const half8v*)&sH[4 * 1296 + cb + ks * 32];
            half8v A5 = *(const half8v*)&sH[5 * 1296 + cb + ks * 32];
            half8v A6 = *(const half8v*)&sH[6 * 1296 + cb + ks * 32];
            half8v A7 = *(const half8v*)&sH[7 * 1296 + cb + ks * 32];
            half8v A8 = *(const half8v*)&sH[8 * 1296 + cb + ks * 32];
            half8v A9 = *(const half8v*)&sH[9 * 1296 + cb + ks * 32];
            half8v Bh0 = (ks == 0) ? B00 : B01;
            half8v Bh1 = (ks == 0) ? B10 : B11;
            half8v Bh2 = (ks == 0) ? B20 : B21;
            // kh = 0: rows m..  kh=1: rows m+1..  kh=2: rows m+2..
            acc[0] = __builtin_amdgcn_mfma_f32_16x16x32_f16(A0, Bh0, acc[0], 0, 0, 0);
            acc[1] = __builtin_amdgcn_mfma_f32_16x16x32_f16(A1, Bh0, acc[1], 0, 0, 0);
            acc[2] = __builtin_amdgcn_mfma_f32_16x16x32_f16(A2, Bh0, acc[2], 0, 0, 0);
            acc[3] = __builtin_amdgcn_mfma_f32_16x16x32_f16(A3, Bh0, acc[3], 0, 0, 0);
            acc[4] = __builtin_amdgcn_mfma_f32_16x16x32_f16(A4, Bh0, acc[4], 0, 0, 0);
            acc[5] = __builtin_amdgcn_mfma_f32_16x16x32_f16(A5, Bh0, acc[5], 0, 0, 0);
            acc[6] = __builtin_amdgcn_mfma_f32_16x16x32_f16(A6, Bh0, acc[6], 0, 0, 0);
            acc[7] = __builtin_amdgcn_mfma_f32_16x16x32_f16(A7, Bh0, acc[7], 0, 0, 0);

            acc[0] = __builtin_amdgcn_mfma_f32_16x16x32_f16(A1, Bh1, acc[0], 0, 0, 0);
            acc[1] = __builtin_amdgcn_mfma_f32_16x16x32_f16(A2, Bh1, acc[1], 0, 0, 0);
            acc[2] = __builtin_amdgcn_mfma_f32_16x16x32_f16(A3, Bh1, acc[2], 0, 0, 0);
            acc[3] = __builtin_amdgcn_mfma_f32_16x16x32_f16(A4, Bh1, acc[3], 0, 0, 0);
            acc[4] = __builtin_amdgcn_mfma_f32_16x16x32_f16(A5, Bh1, acc[4], 0, 0, 0);
            acc[5] = __builtin_amdgcn_mfma_f32_16x16x32_f16(A6, Bh1, acc[5], 0, 0, 0);
            acc[6] = __builtin_amdgcn_mfma_f32_16x16x32_f16(A7, Bh1, acc[6], 0, 0, 0);
            acc[7] = __builtin_amdgcn_mfma_f32_16x16x32_f16(A8, Bh1, acc[7], 0, 0, 0);

            acc[0] = __builtin_amdgcn_mfma_f32_16x16x32_f16(A2, Bh2, acc[0], 0, 0, 0);
            acc[1] = __builtin_amdgcn_mfma_f32_16x16x32_f16(A3, Bh2, acc[1], 0, 0, 0);
            acc[2] = __builtin_amdgcn_mfma_f32_16x16x32_f16(A4, Bh2, acc[2], 0, 0, 0);
            acc[3] = __builtin_amdgcn_mfma_f32_16x16x32_f16(A5, Bh2, acc[3], 0, 0, 0);
            acc[4] = __builtin_amdgcn_mfma_f32_16x16x32_f16(A6, Bh2, acc[4], 0, 0, 0);
            acc[5] = __builtin_amdgcn_mfma_f32_16x16x32_f16(A7, Bh2, acc[5], 0, 0, 0);
            acc[6] = __builtin_amdgcn_mfma_f32_16x16x32_f16(A8, Bh2, acc[6], 0, 0, 0);
            acc[7] = __builtin_amdgcn_mfma_f32_16x16x32_f16(A9, Bh2, acc[7], 0, 0, 0);
        }
    }

    // stats: lane's co = wv*16+l16; sum over 8 m x 4 r; reduce over gq groups
    {
        float s = 0.f, s2 = 0.f;
        #pragma unroll
        for (int m = 0; m < 8; ++m)
            #pragma unroll
            for (int r = 0; r < 4; ++r) {
                float a = acc[m][r];
                s += a; s2 = fmaf(a, a, s2);
            }
        s += __shfl_xor(s, 16); s += __shfl_xor(s, 32);
        s2 += __shfl_xor(s2, 16); s2 += __shfl_xor(s2, 32);
        if (gq == 0) {
            size_t prow = (size_t)blockIdx.y * gridDim.x + blockIdx.x;
            part[prow * 128 + wv * 16 + l16] = s;
            part[prow * 128 + 64 + wv * 16 + l16] = s2;
        }
    }
    // in-register 2x2 pool. acc[m][r] = conv(row r0+m, col c0+gq*4+r), co=wv*16+l16.
    int ch = wv * 16 + l16;
    #pragma unroll
    for (int p = 0; p < 4; ++p) {
        float m01 = fmaxf(fmaxf(acc[2 * p][0], acc[2 * p][1]),
                          fmaxf(acc[2 * p + 1][0], acc[2 * p + 1][1]));
        float m23 = fmaxf(fmaxf(acc[2 * p][2], acc[2 * p][3]),
                          fmaxf(acc[2 * p + 1][2], acc[2 * p + 1][3]));
        int gpr = rt * 4 + p;
        int gpc0 = ctile * 8 + gq * 2;
        if (gpr < PD) {
            size_t rb = (((size_t)gi * PD + gpr) * PD) * 64 + ch;
            if (gpc0 < PD)     pstore(poolout, rb + (size_t)gpc0 * 64, m01);
            if (gpc0 + 1 < PD) pstore(poolout, rb + (size_t)(gpc0 + 1) * 64, m23);
        }
    }
}

// bn_finalize: one (group, channel) per block. grid (ngc, 64).
__global__ __launch_bounds__(256)
void bn_finalize_kernel(const float* __restrict__ part,
                        const float* __restrict__ gamma,
                        const float* __restrict__ beta,
                        float* __restrict__ bnp, float invN, int nby, int gridx) {
    int g = blockIdx.x;
    int c = blockIdx.y;
    int nrows = nby * 32;
    float s = 0.f, s2 = 0.f;
    for (int rr = threadIdx.x; rr < nrows; rr += 256) {
        int by = rr >> 5, i = rr & 31;
        size_t row = (size_t)by * gridx + g * 32 + i;
        s  += part[row * 128 + c];
        s2 += part[row * 128 + 64 + c];
    }
    __shared__ float red[2][256];
    red[0][threadIdx.x] = s; red[1][threadIdx.x] = s2;
    __syncthreads();
    #pragma unroll
    for (int o = 128; o > 0; o >>= 1) {
        if (threadIdx.x < o) {
            red[0][threadIdx.x] += red[0][threadIdx.x + o];
            red[1][threadIdx.x] += red[1][threadIdx.x + o];
        }
        __syncthreads();
    }
    if (threadIdx.x == 0) {
        s = red[0][0]; s2 = red[1][0];
        float mean = s * invN;
        float var  = s2 * invN - mean * mean;
        float sc = gamma[c] * rsqrtf(var + 1e-3f);
        bnp[g * 128 + c] = sc;
        bnp[g * 128 + 64 + c] = beta[c] - sc * mean;
    }
}

// BN+ReLU in place on f16 buffer (L1/L2/L3 paths).
__global__ __launch_bounds__(256)
void bnapplyh_ip_kernel(unsigned short* __restrict__ buf, const float* __restrict__ bnp,
                        int PP, int total) {
    int v = blockIdx.x * 256 + threadIdx.x;
    if (v >= total) return;
    int c4 = (v & 15) * 4;
    int pos = v >> 4;
    int gi = pos / PP;
    int gl = gi >> 5;
    float4 sc = *(const float4*)&bnp[gl * 128 + c4];
    float4 sh = *(const float4*)&bnp[gl * 128 + 64 + c4];
    ushort4 x = *(const ushort4*)&buf[(size_t)pos * 64 + c4];
    ushort4 o;
    o.x = f2h(fmaxf(0.f, fmaf(sc.x, h2f(x.x), sh.x)));
    o.y = f2h(fmaxf(0.f, fmaf(sc.y, h2f(x.y), sh.y)));
    o.z = f2h(fmaxf(0.f, fmaf(sc.z, h2f(x.z), sh.z)));
    o.w = f2h(fmaxf(0.f, fmaf(sc.w, h2f(x.w), sh.w)));
    *(ushort4*)&buf[(size_t)pos * 64 + c4] = o;
}

// In-place f32 BN+ReLU (L4 emb path only).
__global__ __launch_bounds__(256)
void bnapply_kernel(float* __restrict__ buf, const float* __restrict__ bnp,
                    int PP, int total) {
    int v = blockIdx.x * 256 + threadIdx.x;
    if (v >= total) return;
    int c4 = (v & 15) * 4;
    int pos = v >> 4;
    int gi = pos / PP;
    int gl = gi >> 5;
    float4 sc = *(const float4*)&bnp[gl * 128 + c4];
    float4 sh = *(const float4*)&bnp[gl * 128 + 64 + c4];
    float4 x = *(const float4*)&buf[(size_t)pos * 64 + c4];
    float4 o;
    o.x = fmaxf(0.f, fmaf(sc.x, x.x, sh.x));
    o.y = fmaxf(0.f, fmaf(sc.y, x.y, sh.y));
    o.z = fmaxf(0.f, fmaf(sc.z, x.z, sh.z));
    o.w = fmaxf(0.f, fmaf(sc.w, x.w, sh.w));
    *(float4*)&buf[(size_t)pos * 64 + c4] = o;
}

// ---------------- xw projection: tiled split-K f32 GEMM ---------------------
__global__ __launch_bounds__(256)
void xw2_kernel(const float* __restrict__ emb, const float* __restrict__ fk,
                const float* __restrict__ bk, float* __restrict__ xwpart) {
    __shared__ float se[16][200];
    int rt = blockIdx.x;
    int kb = blockIdx.y;
    for (int idx = threadIdx.x; idx < 16 * 200; idx += 256) {
        int r = idx / 200, kk = idx - (idx / 200) * 200;
        se[r][kk] = emb[(size_t)(rt * 16 + r) * 1600 + kb * 200 + kk];
    }
    __syncthreads();
    int j = threadIdx.x & 127;
    int half = threadIdx.x >> 7;
    const float* Wm = half ? bk : fk;
    float acc[16];
    #pragma unroll
    for (int r = 0; r < 16; ++r) acc[r] = 0.f;
    for (int kk = 0; kk < 200; ++kk) {
        float w = Wm[(size_t)(kb * 200 + kk) * 128 + j];
        #pragma unroll
        for (int r = 0; r < 16; ++r) acc[r] = fmaf(se[r][kk], w, acc[r]);
    }
    #pragma unroll
    for (int r = 0; r < 16; ++r)
        xwpart[((size_t)kb * 800 + rt * 16 + r) * 256 + half * 128 + j] = acc[r];
}

__global__ __launch_bounds__(256)
void xwred_kernel(const float* __restrict__ xwpart, float* __restrict__ xwf,
                  float* __restrict__ xwb) {
    int gi = blockIdx.x;
    int c = threadIdx.x;
    float s = 0.f;
    #pragma unroll
    for (int kb = 0; kb < 8; ++kb)
        s += xwpart[((size_t)kb * 800 + gi) * 256 + c];
    if (c < 128) xwf[(size_t)gi * 128 + c] = s;
    else         xwb[(size_t)gi * 128 + (c - 128)] = s;
}

// ---------------- LSTM: latency-optimized, all state in registers -----------
__global__ __launch_bounds__(64, 1)
void lstm_kernel(const float* __restrict__ xwf, const float* __restrict__ xwb,
                 const float* __restrict__ fr, const float* __restrict__ fb,
                 const float* __restrict__ br, const float* __restrict__ bb,
                 float* __restrict__ Hs) {
    int g = blockIdx.x;
    int dir = blockIdx.y;
    int j = threadIdx.x;
    const float* xw = dir ? xwb : xwf;
    const float* Wr = dir ? br : fr;
    const float* bv = dir ? bb : fb;
    float frA[32], frB[32];
    #pragma unroll
    for (int k = 0; k < 32; ++k) {
        frA[k] = Wr[k * 128 + j];
        frB[k] = Wr[k * 128 + 64 + j];
    }
    float bA = bv[j], bB = bv[64 + j];
    float xA[32], xB[32];
    #pragma unroll
    for (int st = 0; st < 32; ++st) {
        int t = dir ? (31 - st) : st;
        xA[st] = xw[((size_t)g * NI + t) * 128 + j];
        xB[st] = xw[((size_t)g * NI + t) * 128 + 64 + j];
    }
    float h = 0.f, c = 0.f;
    #pragma unroll
    for (int st = 0; st < 32; ++st) {
        int t = dir ? (31 - st) : st;
        float a0 = xA[st] + bA, a1 = 0.f, a2 = 0.f, a3 = 0.f;
        float b0 = xB[st] + bB, b1 = 0.f, b2 = 0.f, b3 = 0.f;
        #pragma unroll
        for (int kk = 0; kk < 8; ++kk) {
            float h0 = __shfl(h, kk);
            float h1 = __shfl(h, kk + 8);
            float h2 = __shfl(h, kk + 16);
            float h3 = __shfl(h, kk + 24);
            a0 = fmaf(h0, frA[kk], a0);      b0 = fmaf(h0, frB[kk], b0);
            a1 = fmaf(h1, frA[kk + 8], a1);  b1 = fmaf(h1, frB[kk + 8], b1);
            a2 = fmaf(h2, frA[kk + 16], a2); b2 = fmaf(h2, frB[kk + 16], b2);
            a3 = fmaf(h3, frA[kk + 24], a3); b3 = fmaf(h3, frB[kk + 24], b3);
        }
        float accA = (a0 + a1) + (a2 + a3);
        float accB = (b0 + b1) + (b2 + b3);
        float ig = accA;
        float gg = accB;
        float fg = __shfl(accA, (j & 31) + 32);
        float og = __shfl(accB, (j & 31) + 32);
        float cn = fsigm(fg) * c + fsigm(ig) * ftanh(gg);
        float hn = fsigm(og) * ftanh(cn);
        if (j < 32) {
            c = cn; h = hn;
            Hs[((size_t)g * NI + t) * 64 + dir * 32 + j] = hn;
        }
    }
}

__global__ __launch_bounds__(64, 1)
void sim_kernel(const float* __restrict__ Hs, const int* __restrict__ ysup,
                const int* __restrict__ yq, float* __restrict__ ceb,
                float* __restrict__ eqb) {
    int q = blockIdx.x;
    int i = blockIdx.y;
    int lane = threadIdx.x;
    float qv = Hs[((size_t)(20 + q) * NI + i) * 64 + lane];
    float ls[20];
    for (int s = 0; s < 20; ++s) {
        float sv = Hs[((size_t)s * NI + i) * 64 + lane];
        float d = qv * sv;
        float m = sv * sv;
        #pragma unroll
        for (int o = 32; o > 0; o >>= 1) {
            d += __shfl_xor(d, o);
            m += __shfl_xor(m, o);
        }
        ls[s] = d * rsqrtf(fmaxf(m, 1e-10f));
    }
    if (lane == 0) {
        float mx = -1e30f;
        for (int s = 0; s < 20; ++s) mx = fmaxf(mx, ls[s]);
        float sum = 0.f, sim[20];
        for (int s = 0; s < 20; ++s) { sim[s] = expf(ls[s] - mx); sum += sim[s]; }
        float inv = 1.f / sum;
        float preds[20];
        for (int w = 0; w < 20; ++w) preds[w] = 0.f;
        for (int s = 0; s < 20; ++s) preds[ysup[i * 20 + s]] += sim[s] * inv;
        int y = yq[i * 5 + q];
        float pv = fminf(fmaxf(preds[y], 1e-7f), 1.f - 1e-7f);
        ceb[q * NI + i] = -logf(pv);
        int am = 0; float bm = preds[0];
        for (int w = 1; w < 20; ++w) if (preds[w] > bm) { bm = preds[w]; am = w; }
        eqb[q * NI + i] = (am == y) ? 1.f : 0.f;
    }
}

__global__ __launch_bounds__(64, 1)
void final_kernel(const float* __restrict__ ceb, const float* __restrict__ eqb,
                  float* __restrict__ out) {
    int lane = threadIdx.x;
    float e = 0.f;
    if (lane < 32) {
        float ce = 0.f;
        for (int q = 0; q < 5; ++q) { ce += ceb[q * NI + lane]; e += eqb[q * NI + lane]; }
        out[lane] = ce * 0.2f;
    }
    #pragma unroll
    for (int o = 32; o > 0; o >>= 1) e += __shfl_xor(e, o);
    if (lane == 0) out[32] = e / 160.f;
}

__global__ void sentinel_kernel(float* out) {
    if (threadIdx.x < 33) out[threadIdx.x] = -777.25f;
}

extern "C" void kernel_launch(void* const* d_in, const int* in_sizes, int n_in,
                              void* d_out, int out_size, void* d_ws, size_t ws_size,
                              hipStream_t stream) {
    const float* xs   = (const float*)d_in[0];
    const int*   ysup = (const int*)  d_in[1];
    const float* xq   = (const float*)d_in[2];
    const int*   yq   = (const int*)  d_in[3];
    const float* k[4]  = { (const float*)d_in[4],  (const float*)d_in[8],
                           (const float*)d_in[12], (const float*)d_in[16] };
    const float* ga[4] = { (const float*)d_in[6],  (const float*)d_in[10],
                           (const float*)d_in[14], (const float*)d_in[18] };
    const float* be[4] = { (const float*)d_in[7],  (const float*)d_in[11],
                           (const float*)d_in[15], (const float*)d_in[19] };
    const float* fk = (const float*)d_in[20];
    const float* fr = (const float*)d_in[21];
    const float* fb = (const float*)d_in[22];
    const float* bk = (const float*)d_in[23];
    const float* br = (const float*)d_in[24];
    const float* bb = (const float*)d_in[25];
    float* out = (float*)d_out;

    // per-group float-slot counts (all pools are f16 now)
    const size_t P1   = (size_t)NI * 42 * 42 * 64;
    const size_t P2   = (size_t)NI * 21 * 21 * 64;
    const size_t P3   = (size_t)NI * 10 * 10 * 64;
    const size_t PERG = (P1 + P2 + P3) / 2 + 21u * 32 * 128 + 128;
    const size_t FIXED = 1280000 + 2 * 102400 + 51200 + 320 + 73728 + 1638400;

    const int cands[14] = {25, 20, 18, 16, 14, 12, 10, 8, 6, 5, 4, 3, 2, 1};
    int C = 0;
    for (int t = 0; t < 14; ++t) {
        int c = cands[t];
        if (((size_t)c * PERG + FIXED) * sizeof(float) <= ws_size) { C = c; break; }
    }
    if (C == 0) {
        sentinel_kernel<<<1, 64, 0, stream>>>(out);
        return;
    }

    float* W = (float*)d_ws;
    size_t off = 0;
    unsigned short* pool1h = (unsigned short*)(W + off); off += (size_t)C * P1 / 2;
    unsigned short* pool2h = (unsigned short*)(W + off); off += (size_t)C * P2 / 2;
    unsigned short* pool3h = (unsigned short*)(W + off); off += (size_t)C * P3 / 2;
    float* emb   = W + off; off += 1280000;
    float* part  = W + off; off += 21u * (size_t)C * 32 * 128;
    float* bnp   = W + off; off += (size_t)C * 128;
    unsigned short* w16t = (unsigned short*)(W + off); off += 73728;
    float* xwpart = W + off; off += 1638400;
    float* xwf   = W + off; off += 102400;
    float* xwb   = W + off; off += 102400;
    float* Hs    = W + off; off += 51200;
    float* ceb   = W + off; off += 160;
    float* eqb   = W + off; off += 160;

    // weights -> f16 transposed, once
    for (int l = 1; l < 4; ++l)
        wcvt_kernel<<<9, 256, 0, stream>>>(k[l], w16t + (size_t)l * 9 * 4096);

    for (int g0 = 0; g0 < NG; g0 += C) {
        int ngc = (NG - g0 < C) ? (NG - g0) : C;
        int gx = ngc * 32;

        // L1: f16-MFMA conv3 + stats + in-reg pool -> pool1h (f16 pre-BN); BN in place
        conv3m_kernel<<<dim3(gx, 11), 256, 0, stream>>>(xs, xq, k[0], pool1h, part, g0);
        bn_finalize_kernel<<<dim3(ngc, 64), 256, 0, stream>>>(part, ga[0], be[0], bnp, 1.f / (32.f * 84 * 84), 11, gx);
        bnapplyh_ip_kernel<<<(gx * 42 * 42 * 16 + 255) / 256, 256, 0, stream>>>(pool1h, bnp, 42 * 42, gx * 42 * 42 * 16);

        // L2: halo f16-MFMA conv(42) -> pool2h (f16 pre-BN); BN in place
        conv64m_kernel<42, unsigned short><<<dim3(gx, 18), 256, 0, stream>>>(pool1h, w16t + 9 * 4096, pool2h, part);
        bn_finalize_kernel<<<dim3(ngc, 64), 256, 0, stream>>>(part, ga[1], be[1], bnp, 1.f / (32.f * 42 * 42), 18, gx);
        bnapplyh_ip_kernel<<<(gx * 21 * 21 * 16 + 255) / 256, 256, 0, stream>>>(pool2h, bnp, 21 * 21, gx * 21 * 21 * 16);

        // L3: halo f16-MFMA conv(21) -> pool3h (f16 pre-BN); BN in place
        conv64m_kernel<21, unsigned short><<<dim3(gx, 6), 256, 0, stream>>>(pool2h, w16t + 2 * 9 * 4096, pool3h, part);
        bn_finalize_kernel<<<dim3(ngc, 64), 256, 0, stream>>>(part, ga[2], be[2], bnp, 1.f / (32.f * 21 * 21), 6, gx);
        bnapplyh_ip_kernel<<<(gx * 100 * 16 + 255) / 256, 256, 0, stream>>>(pool3h, bnp, 100, gx * 100 * 16);

        // L4: halo f16-MFMA conv(10) -> emb slice (f32 pre-BN); BN in place
        conv64m_kernel<10, float><<<dim3(gx, 2), 256, 0, stream>>>(pool3h, w16t + 3 * 9 * 4096, emb + (size_t)g0 * 32 * 1600, part);
        bn_finalize_kernel<<<dim3(ngc, 64), 256, 0, stream>>>(part, ga[3], be[3], bnp, 1.f / (32.f * 100), 2, gx);
        bnapply_kernel<<<(gx * 25 * 16 + 255) / 256, 256, 0, stream>>>(emb + (size_t)g0 * 32 * 1600, bnp, 25, gx * 25 * 16);
    }

    // xw projection (split-K GEMM) + reduce
    xw2_kernel<<<dim3(50, 8), 256, 0, stream>>>(emb, fk, bk, xwpart);
    xwred_kernel<<<800, 256, 0, stream>>>(xwpart, xwf, xwb);

    lstm_kernel<<<dim3(NG, 2), 64, 0, stream>>>(xwf, xwb, fr, fb, br, bb, Hs);
    sim_kernel<<<dim3(5, 32), 64, 0, stream>>>(Hs, ysup, yq, ceb, eqb);
    final_kernel<<<1, 64, 0, stream>>>(ceb, eqb, out);
}